// Round 9
// baseline (68.867 us; speedup 1.0000x reference)
//
#include <hip/hip_runtime.h>

typedef _Float16 f16;
typedef __attribute__((ext_vector_type(2))) _Float16 f16x2;
typedef __attribute__((ext_vector_type(4))) _Float16 f16x4;
typedef __attribute__((ext_vector_type(8))) _Float16 f16x8;
typedef __attribute__((ext_vector_type(4))) float    f32x4;

#define NA 32
#define NB 256
#define NT 5
#define ND 256
#define NFIN 80
#define NLAT 128
#define NBEL 64
#define NEG 0.2f

#define W1K 96
#define XSTR 104
#define H1TSTR 40
#define HH1STR 264
#define ALSTR 40

// gnn LDS layout (bytes): Xs [0,6656) and alp [6656,16896) alias hh1 [0,16896)
#define OFF_XS  0
#define OFF_ALP 6656
#define OFF_HH1 0
#define OFF_H1T 16896             // 256*40*2 = 20480
#define OFF_SD  37376             // sA 512B + dA 512B
#define SMEM_SZ 38400

#define MFMA16(a,b,c) __builtin_amdgcn_mfma_f32_16x16x32_f16(a, b, c, 0, 0, 0)

// ---- workspace layout (bytes); d_ws is ~256MB, regions must NOT overlap ----
#define WS_QKV   655360     // qkv f16 [1280][768]  : 655360..2621440
#define WS_W1F   2752512
#define WS_W2F   2801664
#define WS_IPW   2932736
#define WS_OPW   3325952
#define WS_HDW   3457024
#define WS_WSD1  3620864
#define WS_WSD2  3623936    // ..3632128
#define WS_Z2    4194304    // z2 f16 [1280][256] : 4194304..4849664 (clear of all)

// ---------------------------------------------------------------------------
// convert: weights -> f16, plus folded score vectors wsd1/wsd2.
// ---------------------------------------------------------------------------
__global__ void convert_w(const float* __restrict__ W1, const float* __restrict__ W2,
                          const float* __restrict__ ipw, const float* __restrict__ opw,
                          const float* __restrict__ wm, const float* __restrict__ wl,
                          const float* __restrict__ wb,
                          const float* __restrict__ as1, const float* __restrict__ ad1,
                          const float* __restrict__ as2, const float* __restrict__ ad2,
                          f16* __restrict__ W1f, f16* __restrict__ W2f,
                          f16* __restrict__ ipwf, f16* __restrict__ opwf,
                          f16* __restrict__ hdwf,
                          f16* __restrict__ wsd1f, f16* __restrict__ wsd2f)
{
    const int i = blockIdx.x * 256 + threadIdx.x;
    if (i < 24576) {
        const int r = i / W1K, c = i - r * W1K;
        W1f[i] = (c < NFIN) ? (f16)W1[r * NFIN + c] : (f16)0.f;
    } else if (i < 90112) {
        const int j = i - 24576; W2f[j] = (f16)W2[j];
    } else if (i < 286720) {
        const int j = i - 90112; ipwf[j] = (f16)ipw[j];
    } else if (i < 352256) {
        const int j = i - 286720; opwf[j] = (f16)opw[j];
    } else if (i < 434176) {
        const int j = i - 352256;
        hdwf[j] = (f16)(j < 32768 ? wm[j] : (j < 65536 ? wl[j - 32768] : wb[j - 65536]));
    } else if (i < 435712) {
        const int j = i - 434176;          // wsd1: [16][96]
        const int o = j / 96, f = j - o * 96;
        float v = 0.f;
        if (o < 8 && f < NFIN) {
            const int h = o & 3;
            const float* av = (o < 4) ? as1 : ad1;
            for (int cc = 0; cc < 64; ++cc)
                v = fmaf(av[h * 64 + cc], W1[(h * 64 + cc) * NFIN + f], v);
        }
        wsd1f[j] = (f16)v;
    } else if (i < 439808) {
        const int j = i - 435712;          // wsd2: [16][256]
        const int o = j >> 8, k = j & 255;
        float v = 0.f;
        if (o < 8) {
            const int h = o & 3;
            const float* av = (o < 4) ? as2 : ad2;
            for (int cc = 0; cc < 64; ++cc)
                v = fmaf(av[h * 64 + cc], W2[(h * 64 + cc) * ND + k], v);
        }
        wsd2f[j] = (f16)v;
    }
}

// ---------------------------------------------------------------------------
// GNN kernel (unchanged from passing R7 build). Emits z2 = GAT2 pre-W2 agg.
// ---------------------------------------------------------------------------
__global__ __launch_bounds__(256, 2)
void gnn_kernel(const float* __restrict__ x_seq,
                const f16*  __restrict__ W1f,  const f16* __restrict__ wsd1f,
                const float* __restrict__ b1,
                const f16*  __restrict__ wsd2f,
                f16* __restrict__ z2g)
{
    __shared__ __align__(16) unsigned char smem[SMEM_SZ];
    f16*  Xs  = (f16*)(smem + OFF_XS);
    f16*  hh1 = (f16*)(smem + OFF_HH1);
    f16*  alp = (f16*)(smem + OFF_ALP);
    f16*  h1T = (f16*)(smem + OFF_H1T);
    float* sA = (float*)(smem + OFF_SD);
    float* dA = sA + 128;

    const int blk  = blockIdx.x;
    const int b    = blk / NT;
    const int t    = blk % NT;
    const int tid  = threadIdx.x;
    const int wv   = tid >> 6;
    const int lane = tid & 63;
    const int c    = lane & 15;
    const int g    = lane >> 4;
    const int n0   = wv * 64;
    const int kg   = 8 * g;

    f16x8 w1s[3], w1b[3][4];
#pragma unroll
    for (int kt = 0; kt < 3; ++kt) {
        const int k0 = kt * 32 + kg;
        w1s[kt] = *(const f16x8*)(wsd1f + c * W1K + k0);
#pragma unroll
        for (int tn = 0; tn < 4; ++tn)
            w1b[kt][tn] = *(const f16x8*)(W1f + (size_t)(n0 + 16 * tn + c) * W1K + k0);
    }

    const float* xg = x_seq + ((size_t)t * (NB * NA) + (size_t)b * NA) * NFIN;
    for (int idx = tid; idx < 640; idx += 256) {
        const int r = idx / 20, c4 = idx - r * 20;
        const float4 v = ((const float4*)xg)[idx];
        f16x4 h; h.x = (f16)v.x; h.y = (f16)v.y; h.z = (f16)v.z; h.w = (f16)v.w;
        *(f16x4*)(Xs + r * XSTR + c4 * 4) = h;
    }
    if (tid < 128) {
        const int r = tid >> 2, cc = tid & 3;
        f16x4 z; z.x = z.y = z.z = z.w = (f16)0.f;
        *(f16x4*)(Xs + r * XSTR + 80 + cc * 4) = z;
    }
    __syncthreads();

    f32x4 acc1[2][4]; f32x4 accS[2];
#pragma unroll
    for (int m = 0; m < 2; ++m) {
        accS[m] = (f32x4)0.f;
#pragma unroll
        for (int tn = 0; tn < 4; ++tn) acc1[m][tn] = (f32x4)0.f;
    }
#pragma unroll
    for (int kt = 0; kt < 3; ++kt) {
        const int k0 = kt * 32 + kg;
        f16x8 a0 = *(const f16x8*)(Xs + c * XSTR + k0);
        f16x8 a1 = *(const f16x8*)(Xs + (16 + c) * XSTR + k0);
        accS[0] = MFMA16(a0, w1s[kt], accS[0]);
        accS[1] = MFMA16(a1, w1s[kt], accS[1]);
#pragma unroll
        for (int tn = 0; tn < 4; ++tn) {
            acc1[0][tn] = MFMA16(a0, w1b[kt][tn], acc1[0][tn]);
            acc1[1][tn] = MFMA16(a1, w1b[kt][tn], acc1[1][tn]);
        }
    }

    if (c == wv) {
#pragma unroll
        for (int m = 0; m < 2; ++m)
#pragma unroll
            for (int r = 0; r < 4; ++r)
                sA[wv * 32 + 16 * m + 4 * g + r] = accS[m][r];
    } else if (c == wv + 4) {
#pragma unroll
        for (int m = 0; m < 2; ++m)
#pragma unroll
            for (int r = 0; r < 4; ++r)
                dA[wv * 32 + 16 * m + 4 * g + r] = accS[m][r];
    }

#pragma unroll
    for (int m = 0; m < 2; ++m)
#pragma unroll
        for (int tn = 0; tn < 4; ++tn) {
            f16x4 h;
            h.x = (f16)acc1[m][tn][0]; h.y = (f16)acc1[m][tn][1];
            h.z = (f16)acc1[m][tn][2]; h.w = (f16)acc1[m][tn][3];
            *(f16x4*)(h1T + (n0 + 16 * tn + c) * H1TSTR + 16 * m + 4 * g) = h;
        }

    {
        const int j = lane & 31;
        const int half = lane >> 5;
        const float dd = dA[wv * 32 + j];
        const float* sbase = sA + wv * 32 + 16 * half;
        float e[16]; float mx = -1e30f;
#pragma unroll
        for (int i = 0; i < 16; ++i) {
            float v = sbase[i] + dd;
            v = (v >= 0.f) ? v : NEG * v;
            e[i] = v; mx = fmaxf(mx, v);
        }
        mx = fmaxf(mx, __shfl_xor(mx, 32, 64));
        float den = 0.f;
#pragma unroll
        for (int i = 0; i < 16; ++i) { float p = __expf(e[i] - mx); e[i] = p; den += p; }
        den += __shfl_xor(den, 32, 64);
        const float rr = 1.f / den;
        f16* arow = alp + (wv * 32 + j) * ALSTR + 16 * half;
#pragma unroll
        for (int i2 = 0; i2 < 8; ++i2) {
            f16x2 p2; p2.x = (f16)(e[2 * i2] * rr); p2.y = (f16)(e[2 * i2 + 1] * rr);
            *(f16x2*)(arow + 2 * i2) = p2;
        }
    }

    f32x4 accT[4][2];
#pragma unroll
    for (int mt = 0; mt < 4; ++mt)
#pragma unroll
        for (int jt = 0; jt < 2; ++jt) accT[mt][jt] = (f32x4)0.f;
    {
        f16x8 bal0 = *(const f16x8*)(alp + (wv * 32 + c) * ALSTR + kg);
        f16x8 bal1 = *(const f16x8*)(alp + (wv * 32 + 16 + c) * ALSTR + kg);
#pragma unroll
        for (int mt = 0; mt < 4; ++mt) {
            f16x8 ah = *(const f16x8*)(h1T + (n0 + 16 * mt + c) * H1TSTR + kg);
            accT[mt][0] = MFMA16(ah, bal0, accT[mt][0]);
            accT[mt][1] = MFMA16(ah, bal1, accT[mt][1]);
        }
    }

    __syncthreads();

    f32x4 bqa[4];
#pragma unroll
    for (int mt = 0; mt < 4; ++mt)
        bqa[mt] = *(const f32x4*)&b1[n0 + 16 * mt + 4 * g];
#pragma unroll
    for (int mt = 0; mt < 4; ++mt) {
#pragma unroll
        for (int jt = 0; jt < 2; ++jt) {
            f16x4 h;
            h.x = (f16)fmaxf(accT[mt][jt][0] + bqa[mt][0], 0.f);
            h.y = (f16)fmaxf(accT[mt][jt][1] + bqa[mt][1], 0.f);
            h.z = (f16)fmaxf(accT[mt][jt][2] + bqa[mt][2], 0.f);
            h.w = (f16)fmaxf(accT[mt][jt][3] + bqa[mt][3], 0.f);
            *(f16x4*)(hh1 + (16 * jt + c) * HH1STR + n0 + 16 * mt + 4 * g) = h;
        }
    }
    __syncthreads();

    f16x8 w2s[8];
#pragma unroll
    for (int kt = 0; kt < 8; ++kt)
        w2s[kt] = *(const f16x8*)(wsd2f + c * ND + kt * 32 + kg);

    f32x4 accS2[2];
    accS2[0] = (f32x4)0.f; accS2[1] = (f32x4)0.f;
#pragma unroll
    for (int kt = 0; kt < 8; ++kt) {
        const int k0 = kt * 32 + kg;
        f16x8 a0 = *(const f16x8*)(hh1 + c * HH1STR + k0);
        f16x8 a1 = *(const f16x8*)(hh1 + (16 + c) * HH1STR + k0);
        accS2[0] = MFMA16(a0, w2s[kt], accS2[0]);
        accS2[1] = MFMA16(a1, w2s[kt], accS2[1]);
    }

    if (c == wv) {
#pragma unroll
        for (int m = 0; m < 2; ++m)
#pragma unroll
            for (int r = 0; r < 4; ++r)
                sA[wv * 32 + 16 * m + 4 * g + r] = accS2[m][r];
    }
    if (c == wv + 4 && g == 0) dA[wv * 32] = accS2[0][0];

    const float d20 = dA[wv * 32];

    {
        float mx = -1e30f;
#pragma unroll
        for (int i = 0; i < 32; ++i) {
            float v = sA[wv * 32 + i] + d20;
            v = (v >= 0.f) ? v : NEG * v;
            mx = fmaxf(mx, v);
        }
        float den = 0.f;
#pragma unroll
        for (int i = 0; i < 32; ++i) {
            float v = sA[wv * 32 + i] + d20;
            v = (v >= 0.f) ? v : NEG * v;
            den += __expf(v - mx);
        }
        float e0, e1;
        {
            float v = sA[wv * 32 + c] + d20;
            v = (v >= 0.f) ? v : NEG * v;
            e0 = __expf(v - mx);
        }
        {
            float v = sA[wv * 32 + 16 + c] + d20;
            v = (v >= 0.f) ? v : NEG * v;
            e1 = __expf(v - mx);
        }
        const float rden = 1.f / den;
        f16* zo = z2g + (size_t)blk * ND;
#pragma unroll
        for (int mt = 0; mt < 4; ++mt) {
            f32x4 zv;
#pragma unroll
            for (int r = 0; r < 4; ++r) {
                const float h0 = fmaxf(accT[mt][0][r] + bqa[mt][r], 0.f);
                const float h1v = fmaxf(accT[mt][1][r] + bqa[mt][r], 0.f);
                zv[r] = e0 * h0 + e1 * h1v;
            }
#pragma unroll
            for (int r = 0; r < 4; ++r) {
                zv[r] += __shfl_xor(zv[r], 1, 64);
                zv[r] += __shfl_xor(zv[r], 2, 64);
                zv[r] += __shfl_xor(zv[r], 4, 64);
                zv[r] += __shfl_xor(zv[r], 8, 64);
            }
            if (c == 0) {
                f16x4 h;
                h.x = (f16)(zv[0] * rden); h.y = (f16)(zv[1] * rden);
                h.z = (f16)(zv[2] * rden); h.w = (f16)(zv[3] * rden);
                *(f16x4*)(zo + n0 + 16 * mt + 4 * g) = h;
            }
        }
    }
}

// ---------------------------------------------------------------------------
// T1: fused seq+qkv. Block = 32 rows (grid 40). seq lives only in LDS.
// ---------------------------------------------------------------------------
#define TSTR 264
__global__ __launch_bounds__(256, 2)
void seqqkv_kernel(const f16* __restrict__ z2g, const f16* __restrict__ W2f,
                   const float* __restrict__ b2,
                   const f16* __restrict__ ipwf, const float* __restrict__ ipb,
                   f16* __restrict__ qkv)
{
    __shared__ __align__(16) f16 As[32 * TSTR];   // z2 tile
    __shared__ __align__(16) f16 Ss[32 * TSTR];   // seq tile

    const int m0   = blockIdx.x * 32;
    const int tid  = threadIdx.x;
    const int wv   = tid >> 6;
    const int lane = tid & 63;
    const int c    = lane & 15;
    const int g    = lane >> 4;
    const int kg   = 8 * g;
    const int n0   = wv * 64;

    for (int idx = tid; idx < 1024; idx += 256) {
        const int r = idx >> 5, c8 = idx & 31;
        *(f16x8*)(As + r * TSTR + c8 * 8) =
            *(const f16x8*)(z2g + (size_t)(m0 + r) * ND + c8 * 8);
    }
    __syncthreads();

    // ---- Phase A: swapped GEMM. A = W2 rows (chout), B = z2 rows ----
    {
        f32x4 acc[4][2];
#pragma unroll
        for (int tn = 0; tn < 4; ++tn)
#pragma unroll
            for (int jt = 0; jt < 2; ++jt) acc[tn][jt] = (f32x4)0.f;
#pragma unroll
        for (int kt = 0; kt < 8; ++kt) {
            const int k0 = kt * 32 + kg;
            f16x8 bz0 = *(const f16x8*)(As + c * TSTR + k0);
            f16x8 bz1 = *(const f16x8*)(As + (16 + c) * TSTR + k0);
#pragma unroll
            for (int tn = 0; tn < 4; ++tn) {
                f16x8 aw = *(const f16x8*)(W2f + (size_t)(n0 + 16 * tn + c) * ND + k0);
                acc[tn][0] = MFMA16(aw, bz0, acc[tn][0]);
                acc[tn][1] = MFMA16(aw, bz1, acc[tn][1]);
            }
        }
#pragma unroll
        for (int tn = 0; tn < 4; ++tn) {
            const float4 bq = *(const float4*)&b2[n0 + 16 * tn + 4 * g];
#pragma unroll
            for (int jt = 0; jt < 2; ++jt) {
                f16x4 h;
                h.x = (f16)fmaxf(acc[tn][jt][0] + bq.x, 0.f);
                h.y = (f16)fmaxf(acc[tn][jt][1] + bq.y, 0.f);
                h.z = (f16)fmaxf(acc[tn][jt][2] + bq.z, 0.f);
                h.w = (f16)fmaxf(acc[tn][jt][3] + bq.w, 0.f);
                *(f16x4*)(Ss + (16 * jt + c) * TSTR + n0 + 16 * tn + 4 * g) = h;
            }
        }
    }
    __syncthreads();

    // ---- Phase B: qkv, 3 column-chunks of 256 (wave covers 64 of each) ----
#pragma unroll
    for (int ch = 0; ch < 3; ++ch) {
        const int ncol = ch * 256 + n0;
        f32x4 acc[2][4];
#pragma unroll
        for (int m = 0; m < 2; ++m)
#pragma unroll
            for (int tn = 0; tn < 4; ++tn) acc[m][tn] = (f32x4)0.f;
#pragma unroll
        for (int kt = 0; kt < 8; ++kt) {
            const int k0 = kt * 32 + kg;
            f16x8 a0 = *(const f16x8*)(Ss + c * TSTR + k0);
            f16x8 a1 = *(const f16x8*)(Ss + (16 + c) * TSTR + k0);
#pragma unroll
            for (int tn = 0; tn < 4; ++tn) {
                f16x8 bw = *(const f16x8*)(ipwf + (size_t)(ncol + 16 * tn + c) * ND + k0);
                acc[0][tn] = MFMA16(a0, bw, acc[0][tn]);
                acc[1][tn] = MFMA16(a1, bw, acc[1][tn]);
            }
        }
#pragma unroll
        for (int tn = 0; tn < 4; ++tn) {
            const float bias = ipb[ncol + 16 * tn + c];
#pragma unroll
            for (int m = 0; m < 2; ++m)
#pragma unroll
                for (int r = 0; r < 4; ++r) {
                    const int row = m0 + 16 * m + 4 * g + r;
                    qkv[(size_t)row * 768 + ncol + 16 * tn + c] =
                        (f16)(acc[m][tn][r] + bias);
                }
        }
    }
}

// ---------------------------------------------------------------------------
// T2: fused attn + out_proj + heads + belief softmax. Block = 16 batches.
// ---------------------------------------------------------------------------
__global__ __launch_bounds__(256, 2)
void attnfinal_kernel(const f16* __restrict__ qkv,
                      const f16* __restrict__ opwf, const float* __restrict__ opb,
                      const f16* __restrict__ hdwf,
                      const float* __restrict__ bm, const float* __restrict__ blv,
                      const float* __restrict__ bb,
                      float* __restrict__ out)
{
    __shared__ __align__(16) f16 ctx[16 * TSTR];
    __shared__ __align__(16) f16 Fs[16 * TSTR];
    __shared__ __align__(16) float Bs[16 * 68];

    const int bb0  = blockIdx.x * 16;
    const int tid  = threadIdx.x;
    const int wv   = tid >> 6;
    const int lane = tid & 63;
    const int c    = lane & 15;
    const int g    = lane >> 4;
    const int kg   = 8 * g;

    // ---- Phase 1: attention. lane = 4*bq + q4 ----
    {
        const int bq = lane >> 2;
        const int q4 = lane & 3;
        const int chb = wv * 64 + 16 * q4;
        const size_t rowq = (size_t)(bb0 + bq) * 5 + 4;

        f16x8 q0 = *(const f16x8*)(qkv + rowq * 768 + chb);
        f16x8 q1 = *(const f16x8*)(qkv + rowq * 768 + chb + 8);
        f16x8 k0a[NT], k1a[NT], v0a[NT], v1a[NT];
#pragma unroll
        for (int t = 0; t < NT; ++t) {
            const size_t rt = (size_t)(bb0 + bq) * 5 + t;
            k0a[t] = *(const f16x8*)(qkv + rt * 768 + 256 + chb);
            k1a[t] = *(const f16x8*)(qkv + rt * 768 + 256 + chb + 8);
            v0a[t] = *(const f16x8*)(qkv + rt * 768 + 512 + chb);
            v1a[t] = *(const f16x8*)(qkv + rt * 768 + 512 + chb + 8);
        }
        float sc[NT];
#pragma unroll
        for (int t = 0; t < NT; ++t) {
            float s = 0.f;
#pragma unroll
            for (int i = 0; i < 8; ++i) {
                s = fmaf((float)q0[i], (float)k0a[t][i], s);
                s = fmaf((float)q1[i], (float)k1a[t][i], s);
            }
            s += __shfl_xor(s, 1, 64);
            s += __shfl_xor(s, 2, 64);
            sc[t] = s * 0.125f;
        }
        float mx = sc[0];
#pragma unroll
        for (int t = 1; t < NT; ++t) mx = fmaxf(mx, sc[t]);
        float den = 0.f;
        float cacc[16];
#pragma unroll
        for (int i = 0; i < 16; ++i) cacc[i] = 0.f;
#pragma unroll
        for (int t = 0; t < NT; ++t) {
            const float p = __expf(sc[t] - mx);
            den += p;
#pragma unroll
            for (int i = 0; i < 8; ++i) {
                cacc[i]     = fmaf(p, (float)v0a[t][i], cacc[i]);
                cacc[i + 8] = fmaf(p, (float)v1a[t][i], cacc[i + 8]);
            }
        }
        const float rden = 1.f / den;
        f16x8 h0, h1;
#pragma unroll
        for (int i = 0; i < 8; ++i) {
            h0[i] = (f16)(cacc[i] * rden);
            h1[i] = (f16)(cacc[i + 8] * rden);
        }
        *(f16x8*)(ctx + bq * TSTR + chb) = h0;
        *(f16x8*)(ctx + bq * TSTR + chb + 8) = h1;
    }
    __syncthreads();

    // ---- Phase 2: out_proj (swapped, M=16) ----
    {
        const int n0 = wv * 64;
        f32x4 acc[4];
#pragma unroll
        for (int tn = 0; tn < 4; ++tn) acc[tn] = (f32x4)0.f;
#pragma unroll
        for (int kt = 0; kt < 8; ++kt) {
            const int k0 = kt * 32 + kg;
            f16x8 bc = *(const f16x8*)(ctx + c * TSTR + k0);
#pragma unroll
            for (int tn = 0; tn < 4; ++tn) {
                f16x8 aw = *(const f16x8*)(opwf + (size_t)(n0 + 16 * tn + c) * ND + k0);
                acc[tn] = MFMA16(aw, bc, acc[tn]);
            }
        }
#pragma unroll
        for (int tn = 0; tn < 4; ++tn) {
            const float4 bq = *(const float4*)&opb[n0 + 16 * tn + 4 * g];
            f16x4 h;
            h.x = (f16)(acc[tn][0] + bq.x);
            h.y = (f16)(acc[tn][1] + bq.y);
            h.z = (f16)(acc[tn][2] + bq.z);
            h.w = (f16)(acc[tn][3] + bq.w);
            *(f16x4*)(Fs + c * TSTR + n0 + 16 * tn + 4 * g) = h;
        }
    }
    __syncthreads();

    // ---- Phase 3: heads (swapped, 320 cols) ----
    {
        f32x4 acc[5];
#pragma unroll
        for (int fi = 0; fi < 5; ++fi) acc[fi] = (f32x4)0.f;
#pragma unroll
        for (int kt = 0; kt < 8; ++kt) {
            const int k0 = kt * 32 + kg;
            f16x8 bf = *(const f16x8*)(Fs + c * TSTR + k0);
#pragma unroll
            for (int fi = 0; fi < 5; ++fi) {
                const int nf = 5 * wv + fi;
                f16x8 aw = *(const f16x8*)(hdwf + (size_t)(16 * nf + c) * ND + k0);
                acc[fi] = MFMA16(aw, bf, acc[fi]);
            }
        }
#pragma unroll
        for (int fi = 0; fi < 5; ++fi) {
            const int ocol = 16 * (5 * wv + fi) + 4 * g;
            float4 bias;
            if (ocol < 128)       bias = *(const float4*)&bm[ocol];
            else if (ocol < 256)  bias = *(const float4*)&blv[ocol - 128];
            else                  bias = *(const float4*)&bb[ocol - 256];
            float4 v;
            v.x = acc[fi][0] + bias.x; v.y = acc[fi][1] + bias.y;
            v.z = acc[fi][2] + bias.z; v.w = acc[fi][3] + bias.w;
            if (ocol < 128)
                *(float4*)&out[(size_t)(bb0 + c) * NLAT + ocol] = v;
            else if (ocol < 256)
                *(float4*)&out[(size_t)NB * NLAT + (size_t)(bb0 + c) * NLAT + (ocol - 128)] = v;
            else
                *(float4*)&Bs[c * 68 + (ocol - 256)] = v;
        }
    }
    __syncthreads();

    // ---- Phase 4: belief softmax ----
#pragma unroll
    for (int rr = 0; rr < 4; ++rr) {
        const int row = wv * 4 + rr;
        float x = Bs[row * 68 + lane];
        float mm = x;
#pragma unroll
        for (int off = 32; off > 0; off >>= 1) mm = fmaxf(mm, __shfl_xor(mm, off, 64));
        float p = __expf(x - mm);
        float dd = p;
#pragma unroll
        for (int off = 32; off > 0; off >>= 1) dd += __shfl_xor(dd, off, 64);
        out[(size_t)2 * NB * NLAT + (size_t)(bb0 + row) * NBEL + lane] = p / dd;
    }
}

extern "C" void kernel_launch(void* const* d_in, const int* in_sizes, int n_in,
                              void* d_out, int out_size, void* d_ws, size_t ws_size,
                              hipStream_t stream)
{
    (void)in_sizes; (void)n_in; (void)out_size; (void)ws_size;
    const float* x_seq = (const float*)d_in[0];
    const float* W1  = (const float*)d_in[2];
    const float* as1 = (const float*)d_in[3];
    const float* ad1 = (const float*)d_in[4];
    const float* b1  = (const float*)d_in[5];
    const float* W2  = (const float*)d_in[6];
    const float* as2 = (const float*)d_in[7];
    const float* ad2 = (const float*)d_in[8];
    const float* b2  = (const float*)d_in[9];
    const float* ipw = (const float*)d_in[10];
    const float* ipb = (const float*)d_in[11];
    const float* opw = (const float*)d_in[12];
    const float* opb = (const float*)d_in[13];
    const float* wm  = (const float*)d_in[14];
    const float* bm  = (const float*)d_in[15];
    const float* wl  = (const float*)d_in[16];
    const float* bl  = (const float*)d_in[17];
    const float* wb  = (const float*)d_in[18];
    const float* bb  = (const float*)d_in[19];

    char* ws = (char*)d_ws;
    f16* qkv   = (f16*)(ws + WS_QKV);
    f16* z2g   = (f16*)(ws + WS_Z2);
    f16* W1f   = (f16*)(ws + WS_W1F);
    f16* W2f   = (f16*)(ws + WS_W2F);
    f16* ipwf  = (f16*)(ws + WS_IPW);
    f16* opwf  = (f16*)(ws + WS_OPW);
    f16* hdwf  = (f16*)(ws + WS_HDW);
    f16* wsd1f = (f16*)(ws + WS_WSD1);
    f16* wsd2f = (f16*)(ws + WS_WSD2);
    float* out = (float*)d_out;

    hipLaunchKernelGGL(convert_w, dim3(1718), dim3(256), 0, stream,
                       W1, W2, ipw, opw, wm, wl, wb, as1, ad1, as2, ad2,
                       W1f, W2f, ipwf, opwf, hdwf, wsd1f, wsd2f);
    hipLaunchKernelGGL(gnn_kernel, dim3(NB * NT), dim3(256), 0, stream,
                       x_seq, W1f, wsd1f, b1, wsd2f, z2g);
    hipLaunchKernelGGL(seqqkv_kernel, dim3(40), dim3(256), 0, stream,
                       z2g, W2f, b2, ipwf, ipb, qkv);
    hipLaunchKernelGGL(attnfinal_kernel, dim3(16), dim3(256), 0, stream,
                       qkv, opwf, opb, hdwf, bm, bl, bb, out);
}

// Round 10
// 61.907 us; speedup vs baseline: 1.1124x; 1.1124x over previous
//
#include <hip/hip_runtime.h>

typedef _Float16 f16;
typedef __attribute__((ext_vector_type(2))) _Float16 f16x2;
typedef __attribute__((ext_vector_type(4))) _Float16 f16x4;
typedef __attribute__((ext_vector_type(8))) _Float16 f16x8;
typedef __attribute__((ext_vector_type(4))) float    f32x4;

#define NA 32
#define NB 256
#define NT 5
#define ND 256
#define NFIN 80
#define NLAT 128
#define NBEL 64
#define NEG 0.2f

#define W1K 96
#define XSTR 104
#define H1TSTR 40
#define HH1STR 264
#define ALSTR 40

// LDS layout (bytes): Xs [0,6656) and alp [6656,16896) alias hh1 [0,16896)
#define OFF_XS  0
#define OFF_ALP 6656
#define OFF_HH1 0
#define OFF_H1T 16896             // 256*40*2 = 20480
#define OFF_SD  37376             // sA 512B + dA 512B
#define SMEM_SZ 38400

#define MFMA16(a,b,c) __builtin_amdgcn_mfma_f32_16x16x32_f16(a, b, c, 0, 0, 0)

// ---- workspace layout (bytes) ----
#define WS_SEQ   0
#define WS_QKV   655360
#define WS_Z2    655360     // z2 [1280][256] f16; dead before qkv written (alias ok)
#define WS_CTX   2621440
#define WS_W1F   2752512
#define WS_W2F   2801664
#define WS_IPW   2932736
#define WS_OPW   3325952
#define WS_HDW   3457024
#define WS_WSD1  3620864
#define WS_WSD2  3623936

// ---------------------------------------------------------------------------
// convert: weights -> f16, plus folded score vectors wsd1/wsd2.
// ---------------------------------------------------------------------------
__global__ void convert_w(const float* __restrict__ W1, const float* __restrict__ W2,
                          const float* __restrict__ ipw, const float* __restrict__ opw,
                          const float* __restrict__ wm, const float* __restrict__ wl,
                          const float* __restrict__ wb,
                          const float* __restrict__ as1, const float* __restrict__ ad1,
                          const float* __restrict__ as2, const float* __restrict__ ad2,
                          f16* __restrict__ W1f, f16* __restrict__ W2f,
                          f16* __restrict__ ipwf, f16* __restrict__ opwf,
                          f16* __restrict__ hdwf,
                          f16* __restrict__ wsd1f, f16* __restrict__ wsd2f)
{
    const int i = blockIdx.x * 256 + threadIdx.x;
    if (i < 24576) {
        const int r = i / W1K, c = i - r * W1K;
        W1f[i] = (c < NFIN) ? (f16)W1[r * NFIN + c] : (f16)0.f;
    } else if (i < 90112) {
        const int j = i - 24576; W2f[j] = (f16)W2[j];
    } else if (i < 286720) {
        const int j = i - 90112; ipwf[j] = (f16)ipw[j];
    } else if (i < 352256) {
        const int j = i - 286720; opwf[j] = (f16)opw[j];
    } else if (i < 434176) {
        const int j = i - 352256;
        hdwf[j] = (f16)(j < 32768 ? wm[j] : (j < 65536 ? wl[j - 32768] : wb[j - 65536]));
    } else if (i < 435712) {
        const int j = i - 434176;          // wsd1: [16][96]
        const int o = j / 96, f = j - o * 96;
        float v = 0.f;
        if (o < 8 && f < NFIN) {
            const int h = o & 3;
            const float* av = (o < 4) ? as1 : ad1;
            for (int cc = 0; cc < 64; ++cc)
                v = fmaf(av[h * 64 + cc], W1[(h * 64 + cc) * NFIN + f], v);
        }
        wsd1f[j] = (f16)v;
    } else if (i < 439808) {
        const int j = i - 435712;          // wsd2: [16][256]
        const int o = j >> 8, k = j & 255;
        float v = 0.f;
        if (o < 8) {
            const int h = o & 3;
            const float* av = (o < 4) ? as2 : ad2;
            for (int cc = 0; cc < 64; ++cc)
                v = fmaf(av[h * 64 + cc], W2[(h * 64 + cc) * ND + k], v);
        }
        wsd2f[j] = (f16)v;
    }
}

// ---------------------------------------------------------------------------
// GNN kernel. One block per (b,t); wave = head. W2 GEMM folded out: emits
// z2[b,t] = sum_j alpha2[j] * hh1[j]  (the W2 multiply happens in seq_kernel).
// ---------------------------------------------------------------------------
__global__ __launch_bounds__(256, 2)
void gnn_kernel(const float* __restrict__ x_seq,
                const f16*  __restrict__ W1f,  const f16* __restrict__ wsd1f,
                const float* __restrict__ b1,
                const f16*  __restrict__ wsd2f,
                f16* __restrict__ z2g)
{
    __shared__ __align__(16) unsigned char smem[SMEM_SZ];
    f16*  Xs  = (f16*)(smem + OFF_XS);
    f16*  hh1 = (f16*)(smem + OFF_HH1);
    f16*  alp = (f16*)(smem + OFF_ALP);
    f16*  h1T = (f16*)(smem + OFF_H1T);
    float* sA = (float*)(smem + OFF_SD);
    float* dA = sA + 128;

    const int blk  = blockIdx.x;
    const int b    = blk / NT;
    const int t    = blk % NT;
    const int tid  = threadIdx.x;
    const int wv   = tid >> 6;
    const int lane = tid & 63;
    const int c    = lane & 15;
    const int g    = lane >> 4;
    const int n0   = wv * 64;
    const int kg   = 8 * g;

    f16x8 w1s[3], w1b[3][4];
#pragma unroll
    for (int kt = 0; kt < 3; ++kt) {
        const int k0 = kt * 32 + kg;
        w1s[kt] = *(const f16x8*)(wsd1f + c * W1K + k0);
#pragma unroll
        for (int tn = 0; tn < 4; ++tn)
            w1b[kt][tn] = *(const f16x8*)(W1f + (size_t)(n0 + 16 * tn + c) * W1K + k0);
    }

    const float* xg = x_seq + ((size_t)t * (NB * NA) + (size_t)b * NA) * NFIN;
    for (int idx = tid; idx < 640; idx += 256) {
        const int r = idx / 20, c4 = idx - r * 20;
        const float4 v = ((const float4*)xg)[idx];
        f16x4 h; h.x = (f16)v.x; h.y = (f16)v.y; h.z = (f16)v.z; h.w = (f16)v.w;
        *(f16x4*)(Xs + r * XSTR + c4 * 4) = h;
    }
    if (tid < 128) {
        const int r = tid >> 2, cc = tid & 3;
        f16x4 z; z.x = z.y = z.z = z.w = (f16)0.f;
        *(f16x4*)(Xs + r * XSTR + 80 + cc * 4) = z;
    }
    __syncthreads();

    f32x4 acc1[2][4]; f32x4 accS[2];
#pragma unroll
    for (int m = 0; m < 2; ++m) {
        accS[m] = (f32x4)0.f;
#pragma unroll
        for (int tn = 0; tn < 4; ++tn) acc1[m][tn] = (f32x4)0.f;
    }
#pragma unroll
    for (int kt = 0; kt < 3; ++kt) {
        const int k0 = kt * 32 + kg;
        f16x8 a0 = *(const f16x8*)(Xs + c * XSTR + k0);
        f16x8 a1 = *(const f16x8*)(Xs + (16 + c) * XSTR + k0);
        accS[0] = MFMA16(a0, w1s[kt], accS[0]);
        accS[1] = MFMA16(a1, w1s[kt], accS[1]);
#pragma unroll
        for (int tn = 0; tn < 4; ++tn) {
            acc1[0][tn] = MFMA16(a0, w1b[kt][tn], acc1[0][tn]);
            acc1[1][tn] = MFMA16(a1, w1b[kt][tn], acc1[1][tn]);
        }
    }

    if (c == wv) {
#pragma unroll
        for (int m = 0; m < 2; ++m)
#pragma unroll
            for (int r = 0; r < 4; ++r)
                sA[wv * 32 + 16 * m + 4 * g + r] = accS[m][r];
    } else if (c == wv + 4) {
#pragma unroll
        for (int m = 0; m < 2; ++m)
#pragma unroll
            for (int r = 0; r < 4; ++r)
                dA[wv * 32 + 16 * m + 4 * g + r] = accS[m][r];
    }

#pragma unroll
    for (int m = 0; m < 2; ++m)
#pragma unroll
        for (int tn = 0; tn < 4; ++tn) {
            f16x4 h;
            h.x = (f16)acc1[m][tn][0]; h.y = (f16)acc1[m][tn][1];
            h.z = (f16)acc1[m][tn][2]; h.w = (f16)acc1[m][tn][3];
            *(f16x4*)(h1T + (n0 + 16 * tn + c) * H1TSTR + 16 * m + 4 * g) = h;
        }

    {
        const int j = lane & 31;
        const int half = lane >> 5;
        const float dd = dA[wv * 32 + j];
        const float* sbase = sA + wv * 32 + 16 * half;
        float e[16]; float mx = -1e30f;
#pragma unroll
        for (int i = 0; i < 16; ++i) {
            float v = sbase[i] + dd;
            v = (v >= 0.f) ? v : NEG * v;
            e[i] = v; mx = fmaxf(mx, v);
        }
        mx = fmaxf(mx, __shfl_xor(mx, 32, 64));
        float den = 0.f;
#pragma unroll
        for (int i = 0; i < 16; ++i) { float p = __expf(e[i] - mx); e[i] = p; den += p; }
        den += __shfl_xor(den, 32, 64);
        const float rr = 1.f / den;
        f16* arow = alp + (wv * 32 + j) * ALSTR + 16 * half;
#pragma unroll
        for (int i2 = 0; i2 < 8; ++i2) {
            f16x2 p2; p2.x = (f16)(e[2 * i2] * rr); p2.y = (f16)(e[2 * i2 + 1] * rr);
            *(f16x2*)(arow + 2 * i2) = p2;
        }
    }

    f32x4 accT[4][2];
#pragma unroll
    for (int mt = 0; mt < 4; ++mt)
#pragma unroll
        for (int jt = 0; jt < 2; ++jt) accT[mt][jt] = (f32x4)0.f;
    {
        f16x8 bal0 = *(const f16x8*)(alp + (wv * 32 + c) * ALSTR + kg);
        f16x8 bal1 = *(const f16x8*)(alp + (wv * 32 + 16 + c) * ALSTR + kg);
#pragma unroll
        for (int mt = 0; mt < 4; ++mt) {
            f16x8 ah = *(const f16x8*)(h1T + (n0 + 16 * mt + c) * H1TSTR + kg);
            accT[mt][0] = MFMA16(ah, bal0, accT[mt][0]);
            accT[mt][1] = MFMA16(ah, bal1, accT[mt][1]);
        }
    }

    __syncthreads();

    f32x4 bqa[4];
#pragma unroll
    for (int mt = 0; mt < 4; ++mt)
        bqa[mt] = *(const f32x4*)&b1[n0 + 16 * mt + 4 * g];
#pragma unroll
    for (int mt = 0; mt < 4; ++mt) {
#pragma unroll
        for (int jt = 0; jt < 2; ++jt) {
            f16x4 h;
            h.x = (f16)fmaxf(accT[mt][jt][0] + bqa[mt][0], 0.f);
            h.y = (f16)fmaxf(accT[mt][jt][1] + bqa[mt][1], 0.f);
            h.z = (f16)fmaxf(accT[mt][jt][2] + bqa[mt][2], 0.f);
            h.w = (f16)fmaxf(accT[mt][jt][3] + bqa[mt][3], 0.f);
            *(f16x4*)(hh1 + (16 * jt + c) * HH1STR + n0 + 16 * mt + 4 * g) = h;
        }
    }
    __syncthreads();

    f16x8 w2s[8];
#pragma unroll
    for (int kt = 0; kt < 8; ++kt)
        w2s[kt] = *(const f16x8*)(wsd2f + c * ND + kt * 32 + kg);

    f32x4 accS2[2];
    accS2[0] = (f32x4)0.f; accS2[1] = (f32x4)0.f;
#pragma unroll
    for (int kt = 0; kt < 8; ++kt) {
        const int k0 = kt * 32 + kg;
        f16x8 a0 = *(const f16x8*)(hh1 + c * HH1STR + k0);
        f16x8 a1 = *(const f16x8*)(hh1 + (16 + c) * HH1STR + k0);
        accS2[0] = MFMA16(a0, w2s[kt], accS2[0]);
        accS2[1] = MFMA16(a1, w2s[kt], accS2[1]);
    }

    if (c == wv) {
#pragma unroll
        for (int m = 0; m < 2; ++m)
#pragma unroll
            for (int r = 0; r < 4; ++r)
                sA[wv * 32 + 16 * m + 4 * g + r] = accS2[m][r];
    }
    if (c == wv + 4 && g == 0) dA[wv * 32] = accS2[0][0];

    const float d20 = dA[wv * 32];

    {
        float mx = -1e30f;
#pragma unroll
        for (int i = 0; i < 32; ++i) {
            float v = sA[wv * 32 + i] + d20;
            v = (v >= 0.f) ? v : NEG * v;
            mx = fmaxf(mx, v);
        }
        float den = 0.f;
#pragma unroll
        for (int i = 0; i < 32; ++i) {
            float v = sA[wv * 32 + i] + d20;
            v = (v >= 0.f) ? v : NEG * v;
            den += __expf(v - mx);
        }
        float e0, e1;
        {
            float v = sA[wv * 32 + c] + d20;
            v = (v >= 0.f) ? v : NEG * v;
            e0 = __expf(v - mx);
        }
        {
            float v = sA[wv * 32 + 16 + c] + d20;
            v = (v >= 0.f) ? v : NEG * v;
            e1 = __expf(v - mx);
        }
        const float rden = 1.f / den;
        f16* zo = z2g + (size_t)blk * ND;
#pragma unroll
        for (int mt = 0; mt < 4; ++mt) {
            f32x4 zv;
#pragma unroll
            for (int r = 0; r < 4; ++r) {
                const float h0 = fmaxf(accT[mt][0][r] + bqa[mt][r], 0.f);
                const float h1v = fmaxf(accT[mt][1][r] + bqa[mt][r], 0.f);
                zv[r] = e0 * h0 + e1 * h1v;
            }
#pragma unroll
            for (int r = 0; r < 4; ++r) {
                zv[r] += __shfl_xor(zv[r], 1, 64);
                zv[r] += __shfl_xor(zv[r], 2, 64);
                zv[r] += __shfl_xor(zv[r], 4, 64);
                zv[r] += __shfl_xor(zv[r], 8, 64);
            }
            if (c == 0) {
                f16x4 h;
                h.x = (f16)(zv[0] * rden); h.y = (f16)(zv[1] * rden);
                h.z = (f16)(zv[2] * rden); h.w = (f16)(zv[3] * rden);
                *(f16x4*)(zo + n0 + 16 * mt + 4 * g) = h;
            }
        }
    }
}

// ---------------------------------------------------------------------------
// seq GEMM: seq[1280][256] = relu(z2 @ W2^T + b2). Tile 64x128, grid 40.
// ---------------------------------------------------------------------------
#define QASTR 264
__global__ __launch_bounds__(256, 4)
void seq_kernel(const f16* __restrict__ z2g, const f16* __restrict__ W2f,
                const float* __restrict__ b2, f16* __restrict__ seqf)
{
    __shared__ __align__(16) f16 As[64 * QASTR];

    const int bx  = blockIdx.x;
    const int m0  = (bx % 20) * 64;
    const int n0  = (bx / 20) * 128;
    const int tid = threadIdx.x;
    const int wv  = tid >> 6;
    const int lane = tid & 63;
    const int c   = lane & 15;
    const int g   = lane >> 4;
    const int mb  = (wv >> 1) * 32;
    const int nb  = n0 + (wv & 1) * 64;

    for (int idx = tid; idx < 2048; idx += 256) {
        const int r = idx >> 5, c8 = idx & 31;
        *(f16x8*)(As + r * QASTR + c8 * 8) =
            *(const f16x8*)(z2g + (size_t)(m0 + r) * ND + c8 * 8);
    }
    __syncthreads();

    f32x4 acc[2][4];
#pragma unroll
    for (int m = 0; m < 2; ++m)
#pragma unroll
        for (int tn = 0; tn < 4; ++tn) acc[m][tn] = (f32x4)0.f;

#pragma unroll
    for (int kt = 0; kt < 8; ++kt) {
        const int k0 = kt * 32 + 8 * g;
        f16x8 a0 = *(const f16x8*)(As + (mb + c) * QASTR + k0);
        f16x8 a1 = *(const f16x8*)(As + (mb + 16 + c) * QASTR + k0);
#pragma unroll
        for (int tn = 0; tn < 4; ++tn) {
            f16x8 bw = *(const f16x8*)(W2f + (size_t)(nb + 16 * tn + c) * ND + k0);
            acc[0][tn] = MFMA16(a0, bw, acc[0][tn]);
            acc[1][tn] = MFMA16(a1, bw, acc[1][tn]);
        }
    }

    float bias[4];
#pragma unroll
    for (int tn = 0; tn < 4; ++tn) bias[tn] = b2[nb + 16 * tn + c];
#pragma unroll
    for (int m = 0; m < 2; ++m)
#pragma unroll
        for (int tn = 0; tn < 4; ++tn)
#pragma unroll
            for (int r = 0; r < 4; ++r) {
                const int row = m0 + mb + 16 * m + 4 * g + r;
                seqf[(size_t)row * ND + nb + 16 * tn + c] =
                    (f16)fmaxf(acc[m][tn][r] + bias[tn], 0.f);
            }
}

// ---------------------------------------------------------------------------
// qkv GEMM: C[1280][768] = seq @ ipw^T + ipb. Tile 64x128, 4 waves 2x2.
// ---------------------------------------------------------------------------
__global__ __launch_bounds__(256, 4)
void qkv_kernel(const f16* __restrict__ seqf, const f16* __restrict__ ipwf,
                const float* __restrict__ ipb, f16* __restrict__ qkv)
{
    __shared__ __align__(16) f16 As[64 * QASTR];

    const int bx  = blockIdx.x;
    const int m0  = (bx % 20) * 64;
    const int n0  = (bx / 20) * 128;
    const int tid = threadIdx.x;
    const int wv  = tid >> 6;
    const int lane = tid & 63;
    const int c   = lane & 15;
    const int g   = lane >> 4;
    const int mb  = (wv >> 1) * 32;
    const int nb  = n0 + (wv & 1) * 64;

    for (int idx = tid; idx < 2048; idx += 256) {
        const int r = idx >> 5, c8 = idx & 31;
        *(f16x8*)(As + r * QASTR + c8 * 8) =
            *(const f16x8*)(seqf + (size_t)(m0 + r) * ND + c8 * 8);
    }
    __syncthreads();

    f32x4 acc[2][4];
#pragma unroll
    for (int m = 0; m < 2; ++m)
#pragma unroll
        for (int tn = 0; tn < 4; ++tn) acc[m][tn] = (f32x4)0.f;

#pragma unroll
    for (int kt = 0; kt < 8; ++kt) {
        const int k0 = kt * 32 + 8 * g;
        f16x8 a0 = *(const f16x8*)(As + (mb + c) * QASTR + k0);
        f16x8 a1 = *(const f16x8*)(As + (mb + 16 + c) * QASTR + k0);
#pragma unroll
        for (int tn = 0; tn < 4; ++tn) {
            f16x8 bw = *(const f16x8*)(ipwf + (size_t)(nb + 16 * tn + c) * ND + k0);
            acc[0][tn] = MFMA16(a0, bw, acc[0][tn]);
            acc[1][tn] = MFMA16(a1, bw, acc[1][tn]);
        }
    }

    float bias[4];
#pragma unroll
    for (int tn = 0; tn < 4; ++tn) bias[tn] = ipb[nb + 16 * tn + c];
#pragma unroll
    for (int m = 0; m < 2; ++m)
#pragma unroll
        for (int tn = 0; tn < 4; ++tn)
#pragma unroll
            for (int r = 0; r < 4; ++r) {
                const int row = m0 + mb + 16 * m + 4 * g + r;
                qkv[(size_t)row * 768 + nb + 16 * tn + c] =
                    (f16)(acc[m][tn][r] + bias[tn]);
            }
}

// ---------------------------------------------------------------------------
// Attention: block = b, wave = head, lane = channel. Query t=4 only.
// ---------------------------------------------------------------------------
__global__ __launch_bounds__(256, 4)
void attn_kernel(const f16* __restrict__ qkv, f16* __restrict__ ctx)
{
    const int b    = blockIdx.x;
    const int wv   = threadIdx.x >> 6;
    const int lane = threadIdx.x & 63;
    const int ch   = wv * 64 + lane;

    const float q = (float)qkv[(size_t)(b * 5 + 4) * 768 + ch];
    float kv[NT], vv[NT];
#pragma unroll
    for (int t = 0; t < NT; ++t) {
        kv[t] = (float)qkv[(size_t)(b * 5 + t) * 768 + 256 + ch];
        vv[t] = (float)qkv[(size_t)(b * 5 + t) * 768 + 512 + ch];
    }
    float sc[NT];
#pragma unroll
    for (int t = 0; t < NT; ++t) {
        float p = q * kv[t];
#pragma unroll
        for (int off = 32; off > 0; off >>= 1) p += __shfl_xor(p, off, 64);
        sc[t] = p * 0.125f;
    }
    float m = sc[0];
#pragma unroll
    for (int t = 1; t < NT; ++t) m = fmaxf(m, sc[t]);
    float den = 0.f, o = 0.f;
#pragma unroll
    for (int t = 0; t < NT; ++t) {
        float p = __expf(sc[t] - m);
        den += p;
        o = fmaf(p, vv[t], o);
    }
    ctx[(size_t)b * ND + ch] = (f16)(o / den);
}

// ---------------------------------------------------------------------------
// Final: out_proj + heads + belief softmax. Block = 32 batch rows (grid 8).
// ---------------------------------------------------------------------------
#define FASTR 264
__global__ __launch_bounds__(256, 2)
void final_kernel(const f16* __restrict__ ctx,
                  const f16* __restrict__ opwf, const float* __restrict__ opb,
                  const f16* __restrict__ hdwf,
                  const float* __restrict__ bm, const float* __restrict__ blv,
                  const float* __restrict__ bb,
                  float* __restrict__ out)
{
    __shared__ __align__(16) f16 As[32 * FASTR];
    __shared__ __align__(16) f16 Fs[32 * FASTR];
    __shared__ __align__(16) float Bs[32 * 68];

    const int m0   = blockIdx.x * 32;
    const int tid  = threadIdx.x;
    const int wv   = tid >> 6;
    const int lane = tid & 63;
    const int c    = lane & 15;
    const int g    = lane >> 4;

    for (int idx = tid; idx < 1024; idx += 256) {
        const int r = idx >> 5, c8 = idx & 31;
        *(f16x8*)(As + r * FASTR + c8 * 8) =
            *(const f16x8*)(ctx + (size_t)(m0 + r) * ND + c8 * 8);
    }
    __syncthreads();

    {
        f32x4 acc[2][4];
#pragma unroll
        for (int m = 0; m < 2; ++m)
#pragma unroll
            for (int tn = 0; tn < 4; ++tn) acc[m][tn] = (f32x4)0.f;
#pragma unroll
        for (int kt = 0; kt < 8; ++kt) {
            const int k0 = kt * 32 + 8 * g;
            f16x8 a0 = *(const f16x8*)(As + c * FASTR + k0);
            f16x8 a1 = *(const f16x8*)(As + (16 + c) * FASTR + k0);
#pragma unroll
            for (int tn = 0; tn < 4; ++tn) {
                f16x8 bw = *(const f16x8*)(opwf + (size_t)(wv * 64 + 16 * tn + c) * ND + k0);
                acc[0][tn] = MFMA16(a0, bw, acc[0][tn]);
                acc[1][tn] = MFMA16(a1, bw, acc[1][tn]);
            }
        }
        float bias[4];
#pragma unroll
        for (int tn = 0; tn < 4; ++tn) bias[tn] = opb[wv * 64 + 16 * tn + c];
#pragma unroll
        for (int m = 0; m < 2; ++m)
#pragma unroll
            for (int tn = 0; tn < 4; ++tn)
#pragma unroll
                for (int r = 0; r < 4; ++r)
                    Fs[(16 * m + 4 * g + r) * FASTR + wv * 64 + 16 * tn + c] =
                        (f16)(acc[m][tn][r] + bias[tn]);
    }
    __syncthreads();

    {
        f32x4 acc[2][5];
#pragma unroll
        for (int m = 0; m < 2; ++m)
#pragma unroll
            for (int fi = 0; fi < 5; ++fi) acc[m][fi] = (f32x4)0.f;
#pragma unroll
        for (int kt = 0; kt < 8; ++kt) {
            const int k0 = kt * 32 + 8 * g;
            f16x8 a0 = *(const f16x8*)(Fs + c * FASTR + k0);
            f16x8 a1 = *(const f16x8*)(Fs + (16 + c) * FASTR + k0);
#pragma unroll
            for (int fi = 0; fi < 5; ++fi) {
                const int nf = 5 * wv + fi;
                f16x8 bw = *(const f16x8*)(hdwf + (size_t)(16 * nf + c) * ND + k0);
                acc[0][fi] = MFMA16(a0, bw, acc[0][fi]);
                acc[1][fi] = MFMA16(a1, bw, acc[1][fi]);
            }
        }
#pragma unroll
        for (int fi = 0; fi < 5; ++fi) {
            const int ocol = 16 * (5 * wv + fi) + c;
            float bias;
            if (ocol < 128)       bias = bm[ocol];
            else if (ocol < 256)  bias = blv[ocol - 128];
            else                  bias = bb[ocol - 256];
#pragma unroll
            for (int m = 0; m < 2; ++m)
#pragma unroll
                for (int r = 0; r < 4; ++r) {
                    const int row = 16 * m + 4 * g + r;
                    const float v = acc[m][fi][r] + bias;
                    if (ocol < 128)
                        out[(size_t)(m0 + row) * NLAT + ocol] = v;
                    else if (ocol < 256)
                        out[(size_t)NB * NLAT + (size_t)(m0 + row) * NLAT + (ocol - 128)] = v;
                    else
                        Bs[row * 68 + (ocol - 256)] = v;
                }
        }
    }
    __syncthreads();

    for (int rr = 0; rr < 8; ++rr) {
        const int row = wv * 8 + rr;
        float x = Bs[row * 68 + lane];
        float mm = x;
#pragma unroll
        for (int off = 32; off > 0; off >>= 1) mm = fmaxf(mm, __shfl_xor(mm, off, 64));
        float p = __expf(x - mm);
        float dd = p;
#pragma unroll
        for (int off = 32; off > 0; off >>= 1) dd += __shfl_xor(dd, off, 64);
        out[(size_t)2 * NB * NLAT + (size_t)(m0 + row) * NBEL + lane] = p / dd;
    }
}

extern "C" void kernel_launch(void* const* d_in, const int* in_sizes, int n_in,
                              void* d_out, int out_size, void* d_ws, size_t ws_size,
                              hipStream_t stream)
{
    (void)in_sizes; (void)n_in; (void)out_size; (void)ws_size;
    const float* x_seq = (const float*)d_in[0];
    const float* W1  = (const float*)d_in[2];
    const float* as1 = (const float*)d_in[3];
    const float* ad1 = (const float*)d_in[4];
    const float* b1  = (const float*)d_in[5];
    const float* W2  = (const float*)d_in[6];
    const float* as2 = (const float*)d_in[7];
    const float* ad2 = (const float*)d_in[8];
    const float* b2  = (const float*)d_in[9];
    const float* ipw = (const float*)d_in[10];
    const float* ipb = (const float*)d_in[11];
    const float* opw = (const float*)d_in[12];
    const float* opb = (const float*)d_in[13];
    const float* wm  = (const float*)d_in[14];
    const float* bm  = (const float*)d_in[15];
    const float* wl  = (const float*)d_in[16];
    const float* bl  = (const float*)d_in[17];
    const float* wb  = (const float*)d_in[18];
    const float* bb  = (const float*)d_in[19];

    char* ws = (char*)d_ws;
    f16* seqf  = (f16*)(ws + WS_SEQ);
    f16* qkv   = (f16*)(ws + WS_QKV);
    f16* z2g   = (f16*)(ws + WS_Z2);
    f16* ctx   = (f16*)(ws + WS_CTX);
    f16* W1f   = (f16*)(ws + WS_W1F);
    f16* W2f   = (f16*)(ws + WS_W2F);
    f16* ipwf  = (f16*)(ws + WS_IPW);
    f16* opwf  = (f16*)(ws + WS_OPW);
    f16* hdwf  = (f16*)(ws + WS_HDW);
    f16* wsd1f = (f16*)(ws + WS_WSD1);
    f16* wsd2f = (f16*)(ws + WS_WSD2);
    float* out = (float*)d_out;

    hipLaunchKernelGGL(convert_w, dim3(1718), dim3(256), 0, stream,
                       W1, W2, ipw, opw, wm, wl, wb, as1, ad1, as2, ad2,
                       W1f, W2f, ipwf, opwf, hdwf, wsd1f, wsd2f);
    hipLaunchKernelGGL(gnn_kernel, dim3(NB * NT), dim3(256), 0, stream,
                       x_seq, W1f, wsd1f, b1, wsd2f, z2g);
    hipLaunchKernelGGL(seq_kernel, dim3(40), dim3(256), 0, stream,
                       z2g, W2f, b2, seqf);
    hipLaunchKernelGGL(qkv_kernel, dim3(120), dim3(256), 0, stream,
                       seqf, ipwf, ipb, qkv);
    hipLaunchKernelGGL(attn_kernel, dim3(NB), dim3(256), 0, stream, qkv, ctx);
    hipLaunchKernelGGL(final_kernel, dim3(8), dim3(256), 0, stream,
                       ctx, opwf, opb, hdwf, bm, bl, bb, out);
}